// Round 2
// baseline (133.584 us; speedup 1.0000x reference)
//
#include <hip/hip_runtime.h>
#include <math.h>

#define BT     1024
#define NWAVE  16
#define NROW   100
#define DDIM   768
#define RMAX   7            // ceil(100/16) rows per wave
#define EPS_LN 1e-5f
#define EPSF   1e-8f

__device__ __forceinline__ unsigned int f2bf1(float f) {
    union { float f; unsigned int u; } c; c.f = f;
    return (c.u + 0x7FFFu + ((c.u >> 16) & 1u)) >> 16;
}
__device__ __forceinline__ unsigned int packbf(float lo, float hi) {
    return f2bf1(lo) | (f2bf1(hi) << 16);
}
__device__ __forceinline__ float bflo(unsigned int p) {
    union { unsigned int u; float f; } c; c.u = p << 16; return c.f;
}
__device__ __forceinline__ float bfhi(unsigned int p) {
    union { unsigned int u; float f; } c; c.u = p & 0xFFFF0000u; return c.f;
}
__device__ __forceinline__ float wave_sum(float v) {
#pragma unroll
    for (int m = 32; m >= 1; m >>= 1) v += __shfl_xor(v, m, 64);
    return v;
}

extern "C" __global__ void __launch_bounds__(BT, 4)
ccs_kernel(const float* __restrict__ x,
           const float* __restrict__ cc,
           const float* __restrict__ alpha,
           const float* __restrict__ gamma,
           const float* __restrict__ beta,
           const float* __restrict__ thw,
           const float* __restrict__ thb,
           float* __restrict__ out)
{
    __shared__ float Spart[NWAVE][DDIM];   // 48 KB wave partials (reused in pass 3)
    __shared__ float S[DDIM];              // column sums of u
    __shared__ float nrm[NROW];
    __shared__ float dens[NROW];
    __shared__ float w2[NROW];
    __shared__ float Wsh;

    const int tid = threadIdx.x;
    const int w   = tid >> 6;
    const int l   = tid & 63;
    const int b   = blockIdx.x;
    const float* xb = x + (size_t)b * (NROW * DDIM);

    // Per-lane persistent state: packed bf16 normalized rows u[n][d]/|u|,
    // lane's 12 columns are d = k*256 + 4*l + i  (m = k*4+i, pair j = (2j,2j+1)).
    unsigned int xh[RMAX][6];
    float Sl[12];
#pragma unroll
    for (int m = 0; m < 12; ++m) Sl[m] = 0.f;

    // ---------- Pass 1: stream x, LayerNorm, L2-normalize, keep in regs ----------
#pragma unroll
    for (int r = 0; r < RMAX; ++r) {
        const int n = w + r * NWAVE;          // wave-uniform
        if (n < NROW) {
            const float* xr = xb + n * DDIM;
            float xf[12];
            *(float4*)&xf[0] = *(const float4*)(xr +   0 + 4 * l);
            *(float4*)&xf[4] = *(const float4*)(xr + 256 + 4 * l);
            *(float4*)&xf[8] = *(const float4*)(xr + 512 + 4 * l);

            float s = 0.f, sq = 0.f;
#pragma unroll
            for (int m = 0; m < 12; ++m) { s += xf[m]; sq += xf[m] * xf[m]; }
#pragma unroll
            for (int msk = 32; msk >= 1; msk >>= 1) {
                s  += __shfl_xor(s,  msk, 64);
                sq += __shfl_xor(sq, msk, 64);
            }
            const float mu   = s * (1.0f / DDIM);
            const float var  = sq * (1.0f / DDIM) - mu * mu;
            const float rstd = rsqrtf(var + EPS_LN);

            float gf[12], bfv[12];
            *(float4*)&gf[0]  = *(const float4*)(gamma +   0 + 4 * l);
            *(float4*)&gf[4]  = *(const float4*)(gamma + 256 + 4 * l);
            *(float4*)&gf[8]  = *(const float4*)(gamma + 512 + 4 * l);
            *(float4*)&bfv[0] = *(const float4*)(beta  +   0 + 4 * l);
            *(float4*)&bfv[4] = *(const float4*)(beta  + 256 + 4 * l);
            *(float4*)&bfv[8] = *(const float4*)(beta  + 512 + 4 * l);

            float q = 0.f;
#pragma unroll
            for (int m = 0; m < 12; ++m) {
                float v = (xf[m] - mu) * rstd * gf[m] + bfv[m];
                xf[m] = v;
                q += v * v;
            }
            q = wave_sum(q);
            const float nr  = sqrtf(q);
            const float inv = (nr > 0.f) ? (1.0f / nr) : 0.f;
#pragma unroll
            for (int m = 0; m < 12; ++m) { xf[m] *= inv; Sl[m] += xf[m]; }
#pragma unroll
            for (int j = 0; j < 6; ++j)
                xh[r][j] = packbf(xf[2 * j], xf[2 * j + 1]);
            if (l == 0) nrm[n] = nr;
        }
    }

    // ---------- S[d] = sum_n u[n][d] : wave partials -> tree reduce ----------
#pragma unroll
    for (int k = 0; k < 3; ++k)
        *(float4*)&Spart[w][k * 256 + 4 * l] = *(float4*)&Sl[k * 4];
    __syncthreads();
    if (tid < DDIM) {
        float a = 0.f;
#pragma unroll
        for (int ww = 0; ww < NWAVE; ++ww) a += Spart[ww][tid];
        S[tid] = a;
    }
    __syncthreads();

    // ---------- Pass 2a: density[n] = u_n . S ----------
    float Sv[12];
#pragma unroll
    for (int k = 0; k < 3; ++k)
        *(float4*)&Sv[k * 4] = *(const float4*)&S[k * 256 + 4 * l];
#pragma unroll
    for (int r = 0; r < RMAX; ++r) {
        const int n = w + r * NWAVE;
        if (n < NROW) {
            float dot = 0.f;
#pragma unroll
            for (int j = 0; j < 6; ++j)
                dot += bflo(xh[r][j]) * Sv[2 * j] + bfhi(xh[r][j]) * Sv[2 * j + 1];
            dot = wave_sum(dot);
            if (l == 0) dens[n] = dot;
        }
    }
    __syncthreads();

    // ---------- Pass 2b: min-max, sigmoid threshold, gate (wave 0) ----------
    if (w == 0) {
        const float va = dens[l];
        const bool  hb = (l < NROW - 64);
        const float vb = hb ? dens[64 + l] : 0.f;

        float mxv = hb ? fmaxf(va, vb) : va;
        float mnv = hb ? fminf(va, vb) : va;
#pragma unroll
        for (int m = 32; m >= 1; m >>= 1) {
            mxv = fmaxf(mxv, __shfl_xor(mxv, m, 64));
            mnv = fminf(mnv, __shfl_xor(mnv, m, 64));
        }
        const float rng = 1.0f / (mxv - mnv + EPSF);
        const float ra  = (va - mnv) * rng;
        const float rb  = (vb - mnv) * rng;

        float td = ra * thw[l] + (hb ? rb * thw[64 + l] : 0.f);
        td = wave_sum(td);
        const float z  = td + thb[0];
        const float th = alpha[0] / (1.0f + expf(-z));

        const float ga = fmaxf(ra - th, 0.f);
        const float gb = hb ? fmaxf(rb - th, 0.f) : 0.f;
        const float sg = wave_sum(ga + gb);
        const float wf = 1.0f / (sg + EPSF);

        w2[l] = ga * wf * nrm[l];
        if (hb) w2[64 + l] = gb * wf * nrm[64 + l];
        if (l == 0) Wsh = sg * wf;
    }
    __syncthreads();

    // ---------- Pass 3: shift[d] = sum_n w2[n]*u[n][d] ----------
    float acc[12];
#pragma unroll
    for (int m = 0; m < 12; ++m) acc[m] = 0.f;
#pragma unroll
    for (int r = 0; r < RMAX; ++r) {
        const int n = w + r * NWAVE;
        if (n < NROW) {
            const float wv = w2[n];
#pragma unroll
            for (int j = 0; j < 6; ++j) {
                acc[2 * j]     += wv * bflo(xh[r][j]);
                acc[2 * j + 1] += wv * bfhi(xh[r][j]);
            }
        }
    }
#pragma unroll
    for (int k = 0; k < 3; ++k)
        *(float4*)&Spart[w][k * 256 + 4 * l] = *(float4*)&acc[k * 4];
    __syncthreads();

    if (tid < DDIM) {
        float a = 0.f;
#pragma unroll
        for (int ww = 0; ww < NWAVE; ++ww) a += Spart[ww][tid];
        const float c = cc[(size_t)b * DDIM + tid];
        out[(size_t)b * DDIM + tid] = c + (a - c * Wsh) * (1.0f / NROW);
    }
}

extern "C" void kernel_launch(void* const* d_in, const int* in_sizes, int n_in,
                              void* d_out, int out_size, void* d_ws, size_t ws_size,
                              hipStream_t stream) {
    const float* x     = (const float*)d_in[0];
    const float* cc    = (const float*)d_in[1];
    const float* alpha = (const float*)d_in[2];
    const float* gamma = (const float*)d_in[3];
    const float* beta  = (const float*)d_in[4];
    const float* thw   = (const float*)d_in[5];
    const float* thb   = (const float*)d_in[6];
    float* out = (float*)d_out;

    ccs_kernel<<<1024, BT, 0, stream>>>(x, cc, alpha, gamma, beta, thw, thb, out);
}